// Round 1
// baseline (284.835 us; speedup 1.0000x reference)
//
#include <hip/hip_runtime.h>

using half8 = __attribute__((ext_vector_type(8))) _Float16;
using f32x4 = __attribute__((ext_vector_type(4))) float;
using f4vec = __attribute__((ext_vector_type(4))) float;

#define LOG2E 1.44269504088896340f

__device__ __forceinline__ float fast_exp(float x) {
    return __builtin_amdgcn_exp2f(LOG2E * x);
}
__device__ __forceinline__ float sigmoidf(float v) {
    return __builtin_amdgcn_rcpf(1.f + __builtin_amdgcn_exp2f(-LOG2E * v));
}

// ---------------- preprocess: softmax rows + exp(log_a) scaling ---------------
// Emits 13 fp16 [128][128] matrices into G (pre-swizzled: element (r,i) at byte
// r*256 + ((i*2) ^ ((r&7)<<4)) ), plus a0x/a0t (first layer, in=2) and uLs.
// Matrix order: m=0: softmax(w0); m=1+2l: exp(laM[l])*softmax(uM[l]); m=2+2l: softmax(wM[l])
__global__ void prep_kernel(const float* __restrict__ u0, const float* __restrict__ w0,
                            const float* __restrict__ la0,
                            const float* __restrict__ uM, const float* __restrict__ wM,
                            const float* __restrict__ laM,
                            const float* __restrict__ uL, const float* __restrict__ laL,
                            _Float16* __restrict__ G, float* __restrict__ a0x,
                            float* __restrict__ a0t, float* __restrict__ uLso)
{
    const int b = blockIdx.x, lane = threadIdx.x;
    if (b < 1664) {
        const int m = b >> 7, r = b & 127;
        const float* src;
        float scale = 1.f;
        if (m == 0) {
            src = w0 + r * 128;
        } else if (m & 1) {
            int l = (m - 1) >> 1;
            src = uM + (l * 128 + r) * 128;
            scale = fast_exp(laM[l * 128 + r]);
        } else {
            int l = (m - 2) >> 1;
            src = wM + (l * 128 + r) * 128;
        }
        float v0 = src[lane], v1 = src[lane + 64];
        float mx = fmaxf(v0, v1);
#pragma unroll
        for (int o = 32; o; o >>= 1) mx = fmaxf(mx, __shfl_xor(mx, o));
        float e0 = __builtin_amdgcn_exp2f(LOG2E * (v0 - mx));
        float e1 = __builtin_amdgcn_exp2f(LOG2E * (v1 - mx));
        float ssum = e0 + e1;
#pragma unroll
        for (int o = 32; o; o >>= 1) ssum += __shfl_xor(ssum, o);
        float inv = scale / ssum;
        char* base = (char*)G + b * 256;   // (m*128 + r) * 256 bytes
        const int sw = (r & 7) << 4;
        *(_Float16*)(base + ((2 * lane) ^ sw))       = (_Float16)(e0 * inv);
        *(_Float16*)(base + ((2 * lane + 128) ^ sw)) = (_Float16)(e1 * inv);
    } else if (b == 1664) {
        // first layer: A0 = exp(la0) * softmax(u0 rows of 2)
        for (int j = lane; j < 128; j += 64) {
            float q0 = u0[2 * j], q1 = u0[2 * j + 1];
            float mx = fmaxf(q0, q1);
            float e0 = fast_exp(q0 - mx), e1 = fast_exp(q1 - mx);
            float a = fast_exp(la0[j]) / (e0 + e1);
            a0x[j] = a * e0;
            a0t[j] = a * e1;
        }
    } else {
        // last layer: uLs = exp(laL) * softmax(uL row of 128)
        float v0 = uL[lane], v1 = uL[lane + 64];
        float mx = fmaxf(v0, v1);
#pragma unroll
        for (int o = 32; o; o >>= 1) mx = fmaxf(mx, __shfl_xor(mx, o));
        float e0 = __builtin_amdgcn_exp2f(LOG2E * (v0 - mx));
        float e1 = __builtin_amdgcn_exp2f(LOG2E * (v1 - mx));
        float ssum = e0 + e1;
#pragma unroll
        for (int o = 32; o; o >>= 1) ssum += __shfl_xor(ssum, o);
        float aL = fast_exp(laL[0]) / ssum;
        uLso[lane]      = e0 * aL;
        uLso[lane + 64] = e1 * aL;
    }
}

// ---------------- main fused kernel ----------------
// Block: 256 threads (4 waves), BM=64 rows. LDS: H (16KB) | S (16KB) | W (32KB).
// H/S hold the running activation [64][128] fp16, swizzled. W holds the current
// 128x128 fp16 weight (pre-swizzled, copied linearly from ws).
constexpr int BM   = 64;
constexpr int HOFF = 0;
constexpr int SOFF = 16384;
constexpr int WOFF = 32768;

__device__ __forceinline__ void stage_wt(char* sm, const _Float16* g, int tid) {
    const f4vec* src = (const f4vec*)g;
    f4vec* dst = (f4vec*)(sm + WOFF);
#pragma unroll
    for (int i = 0; i < 8; ++i) dst[tid + i * 256] = src[tid + i * 256];
}

// C[64x128] = act( src[64x128] @ W^T + bias ), written fp16-swizzled to dst.
// mfma_f32_16x16x32_f16; A: row=lane&15, k=(lane>>4)*8+j ; B: col=lane&15, same k;
// C: col=lane&15, row=(lane>>4)*4+reg.
template <bool SIG, bool BIAS>
__device__ __forceinline__ void gemm128(char* sm, int srcOff, int dstOff,
                                        const float* __restrict__ bias,
                                        int wave, int lane)
{
    f32x4 acc[8] = {};
    const int l15 = lane & 15, kg = lane >> 4;
    const int rA  = wave * 16 + l15;
    const int swA = (rA & 7) << 4;
    const int swB = (l15 & 7) << 4;
    const char* srcA = sm + srcOff + rA * 256;
    const char* srcB = sm + WOFF + l15 * 256;
#pragma unroll
    for (int ks = 0; ks < 4; ++ks) {
        const int koff = ks * 64 + kg * 16;
        half8 a = *(const half8*)(srcA + (koff ^ swA));
#pragma unroll
        for (int ct = 0; ct < 8; ++ct) {
            half8 b = *(const half8*)(srcB + ct * 4096 + (koff ^ swB));
            acc[ct] = __builtin_amdgcn_mfma_f32_16x16x32_f16(a, b, acc[ct], 0, 0, 0);
        }
    }
#pragma unroll
    for (int ct = 0; ct < 8; ++ct) {
        const int col = ct * 16 + l15;
        float bv = BIAS ? bias[col] : 0.f;
#pragma unroll
        for (int j = 0; j < 4; ++j) {
            const int row = wave * 16 + kg * 4 + j;
            float v = acc[ct][j] + bv;
            if (SIG) v = sigmoidf(v);
            *(_Float16*)(sm + dstOff + row * 256 + ((col * 2) ^ ((row & 7) << 4))) = (_Float16)v;
        }
    }
}

__global__ __launch_bounds__(256, 2)
void mono_main(const float* __restrict__ x, const float* __restrict__ fy0,
               const float* __restrict__ b0, const float* __restrict__ bM,
               const float* __restrict__ bL,
               const float* __restrict__ W1, const float* __restrict__ b1,
               const float* __restrict__ W2, const float* __restrict__ b2,
               const float* __restrict__ W3, const float* __restrict__ b3,
               const _Float16* __restrict__ G, const float* __restrict__ a0x,
               const float* __restrict__ a0t, const float* __restrict__ uLs,
               float* __restrict__ out)
{
    __shared__ char sm[65536];
    const int tid  = threadIdx.x;
    const int lane = tid & 63, wave = tid >> 6;
    const int row0 = blockIdx.x * BM;

    // scratch carved from the H region's tail (h1 only uses [0,12800))
    float* thetaS = (float*)(sm + HOFF + 12800);  // 64 floats
    float* xv     = thetaS + 64;                  // 64 floats

    // ---- stage MLP weights (fp32) into W region ----
    float* wbuf = (float*)(sm + WOFF);
    for (int i = tid; i < 50; i += 256) {
        wbuf[i]        = W1[i];
        wbuf[50 + i]   = b1[i];
        wbuf[2600 + i] = b2[i];
        wbuf[2650 + i] = W3[i];
    }
    for (int i = tid; i < 2500; i += 256) wbuf[100 + i] = W2[i];
    if (tid == 0) wbuf[2750] = b3[0];
    if (tid < 64) xv[tid] = x[row0 + tid];
    __syncthreads();

    // ---- MLP: fy0 -> h1[64][50] -> h2[64][50] -> theta[64] ----
    float* Hf = (float*)(sm + HOFF);
    float* Sf = (float*)(sm + SOFF);
    for (int idx = tid; idx < 64 * 50; idx += 256) {
        int r = idx / 50, j = idx - r * 50;
        Hf[idx] = fmaxf(fy0[row0 + r] * wbuf[j] + wbuf[50 + j], 0.f);
    }
    __syncthreads();
    for (int idx = tid; idx < 64 * 50; idx += 256) {
        int r = idx / 50, j = idx - r * 50;
        const float* w2 = wbuf + 100 + j * 50;
        const float* h1 = Hf + r * 50;
        float s = wbuf[2600 + j];
        for (int i = 0; i < 50; ++i) s += w2[i] * h1[i];
        Sf[idx] = fmaxf(s, 0.f);
    }
    __syncthreads();
    if (tid < 64) {
        const float* h2 = Sf + tid * 50;
        float s = wbuf[2750];
        for (int i = 0; i < 50; ++i) s += wbuf[2650 + i] * h2[i];
        thetaS[tid] = s;
    }
    __syncthreads();

    // ---- first layer (in=2): S = sigmoid(a0x*x + a0t*theta + b0), fp16 swizzled ----
    for (int idx = tid; idx < 64 * 128; idx += 256) {
        int r = idx >> 7, j = idx & 127;
        float v = a0x[j] * xv[r] + a0t[j] * thetaS[r] + b0[j];
        float s = sigmoidf(v);
        *(_Float16*)(sm + SOFF + r * 256 + ((j * 2) ^ ((r & 7) << 4))) = (_Float16)s;
    }
    stage_wt(sm, G, tid);  // G0 = softmax(w0)
    __syncthreads();
    gemm128<false, false>(sm, SOFF, HOFF, nullptr, wave, lane);  // H = S @ W0^T
    __syncthreads();

    // ---- 6 middle layers ----
    for (int l = 0; l < 6; ++l) {
        stage_wt(sm, G + (1 + 2 * l) * 16384, tid);  // A_l
        __syncthreads();
        gemm128<true, true>(sm, HOFF, SOFF, bM + l * 128, wave, lane);  // S = sig(H@A^T+b)
        __syncthreads();
        stage_wt(sm, G + (2 + 2 * l) * 16384, tid);  // W_l
        __syncthreads();
        gemm128<false, false>(sm, SOFF, HOFF, nullptr, wave, lane);     // H = S @ W^T
        __syncthreads();
    }

    // ---- last layer: out = sigmoid(H . uLs + bL) ----
    {
        int r = tid >> 2, part = tid & 3;
        const int sw = (r & 7) << 4;
        float s = 0.f;
#pragma unroll
        for (int v = 0; v < 4; ++v) {
            half8 hv = *(const half8*)(sm + HOFF + r * 256 + ((part * 64 + v * 16) ^ sw));
#pragma unroll
            for (int e = 0; e < 8; ++e) s += (float)hv[e] * uLs[part * 32 + v * 8 + e];
        }
        s += __shfl_xor(s, 1);
        s += __shfl_xor(s, 2);
        if (part == 0) out[row0 + r] = sigmoidf(s + bL[0]);
    }
}

extern "C" void kernel_launch(void* const* d_in, const int* in_sizes, int n_in,
                              void* d_out, int out_size, void* d_ws, size_t ws_size,
                              hipStream_t stream)
{
    const float* x   = (const float*)d_in[0];
    const float* fy0 = (const float*)d_in[1];
    const float* u0  = (const float*)d_in[2];
    const float* w0  = (const float*)d_in[3];
    const float* la0 = (const float*)d_in[4];
    const float* b0  = (const float*)d_in[5];
    const float* uM  = (const float*)d_in[6];
    const float* wM  = (const float*)d_in[7];
    const float* laM = (const float*)d_in[8];
    const float* bM  = (const float*)d_in[9];
    const float* uL  = (const float*)d_in[10];
    // d_in[11] = wL: softmax over a [1,1] row == 1.0, no-op
    const float* laL = (const float*)d_in[12];
    const float* bL  = (const float*)d_in[13];
    const float* W1  = (const float*)d_in[14];
    const float* b1  = (const float*)d_in[15];
    const float* W2  = (const float*)d_in[16];
    const float* b2  = (const float*)d_in[17];
    const float* W3  = (const float*)d_in[18];
    const float* b3  = (const float*)d_in[19];
    float* out = (float*)d_out;

    _Float16* G = (_Float16*)d_ws;                       // 13 * 32 KB
    float* a0x  = (float*)((char*)d_ws + 13 * 32768);
    float* a0t  = a0x + 128;
    float* uLso = a0t + 128;

    prep_kernel<<<1666, 64, 0, stream>>>(u0, w0, la0, uM, wM, laM, uL, laL,
                                         G, a0x, a0t, uLso);
    mono_main<<<131072 / BM, 256, 0, stream>>>(x, fy0, b0, bM, bL,
                                               W1, b1, W2, b2, W3, b3,
                                               G, a0x, a0t, uLso, out);
}

// Round 2
// 245.806 us; speedup vs baseline: 1.1588x; 1.1588x over previous
//
#include <hip/hip_runtime.h>

using half8 = __attribute__((ext_vector_type(8))) _Float16;
using f32x4 = __attribute__((ext_vector_type(4))) float;

#define LOG2E 1.44269504088896340f

__device__ __forceinline__ float fast_exp(float x) {
    return __builtin_amdgcn_exp2f(LOG2E * x);
}
__device__ __forceinline__ float sigmoidf(float v) {
    return __builtin_amdgcn_rcpf(1.f + __builtin_amdgcn_exp2f(-LOG2E * v));
}

// ---------------- preprocess ----------------
// G: 13 fp16 [128][128] row-major matrices (plain, NOT swizzled — consumed as
// global->register B-fragments). m=0: softmax(w0); m=1+2l: exp(laM)*softmax(uM);
// m=2+2l: softmax(wM). Plus: W2h [64][64] fp16 (padded), a0x/a0t, uLs,
// W1p/b1p/W3p (padded to 64).
__global__ void prep_kernel(const float* __restrict__ u0, const float* __restrict__ w0,
                            const float* __restrict__ la0,
                            const float* __restrict__ uM, const float* __restrict__ wM,
                            const float* __restrict__ laM,
                            const float* __restrict__ uL, const float* __restrict__ laL,
                            const float* __restrict__ W1, const float* __restrict__ b1,
                            const float* __restrict__ W2, const float* __restrict__ W3,
                            _Float16* __restrict__ G, _Float16* __restrict__ W2h,
                            float* __restrict__ a0x, float* __restrict__ a0t,
                            float* __restrict__ uLso,
                            float* __restrict__ W1p, float* __restrict__ b1p,
                            float* __restrict__ W3p)
{
    const int b = blockIdx.x, lane = threadIdx.x;
    if (b < 1664) {
        const int m = b >> 7, r = b & 127;
        const float* src;
        float scale = 1.f;
        if (m == 0) {
            src = w0 + r * 128;
        } else if (m & 1) {
            int l = (m - 1) >> 1;
            src = uM + (l * 128 + r) * 128;
            scale = fast_exp(laM[l * 128 + r]);
        } else {
            int l = (m - 2) >> 1;
            src = wM + (l * 128 + r) * 128;
        }
        float v0 = src[lane], v1 = src[lane + 64];
        float mx = fmaxf(v0, v1);
#pragma unroll
        for (int o = 32; o; o >>= 1) mx = fmaxf(mx, __shfl_xor(mx, o));
        float e0 = __builtin_amdgcn_exp2f(LOG2E * (v0 - mx));
        float e1 = __builtin_amdgcn_exp2f(LOG2E * (v1 - mx));
        float ssum = e0 + e1;
#pragma unroll
        for (int o = 32; o; o >>= 1) ssum += __shfl_xor(ssum, o);
        float inv = scale / ssum;
        _Float16* dst = G + b * 128;
        dst[lane]      = (_Float16)(e0 * inv);
        dst[lane + 64] = (_Float16)(e1 * inv);
    } else if (b == 1664) {
        // first layer (in=2) + MLP padded weight vectors
        for (int j = lane; j < 128; j += 64) {
            float q0 = u0[2 * j], q1 = u0[2 * j + 1];
            float mx = fmaxf(q0, q1);
            float e0 = fast_exp(q0 - mx), e1 = fast_exp(q1 - mx);
            float a = fast_exp(la0[j]) / (e0 + e1);
            a0x[j] = a * e0;
            a0t[j] = a * e1;
        }
        W1p[lane] = (lane < 50) ? W1[lane] : 0.f;
        b1p[lane] = (lane < 50) ? b1[lane] : 0.f;
        W3p[lane] = (lane < 50) ? W3[lane] : 0.f;
    } else if (b == 1665) {
        // last layer: uLs = exp(laL) * softmax(uL row of 128)
        float v0 = uL[lane], v1 = uL[lane + 64];
        float mx = fmaxf(v0, v1);
#pragma unroll
        for (int o = 32; o; o >>= 1) mx = fmaxf(mx, __shfl_xor(mx, o));
        float e0 = __builtin_amdgcn_exp2f(LOG2E * (v0 - mx));
        float e1 = __builtin_amdgcn_exp2f(LOG2E * (v1 - mx));
        float ssum = e0 + e1;
#pragma unroll
        for (int o = 32; o; o >>= 1) ssum += __shfl_xor(ssum, o);
        float aL = fast_exp(laL[0]) / ssum;
        uLso[lane]      = e0 * aL;
        uLso[lane + 64] = e1 * aL;
    } else {
        // W2h [64][64] fp16 zero-padded from W2 [50][50]
        int j = lane;
        for (int i = 0; i < 64; ++i)
            W2h[j * 64 + i] = (j < 50 && i < 50) ? (_Float16)W2[j * 50 + i] : (_Float16)0.f;
    }
}

// ---------------- main fused kernel ----------------
// 256 threads (4 waves), BM=64 rows/block. LDS: H (16KB) + S (16KB) fp16
// swizzled activations only. Weights consumed global(L2)->registers.
constexpr int BM = 64;

__device__ __forceinline__ void wr_act(char* dst, int row, int col, float v) {
    *(_Float16*)(dst + row * 256 + ((col * 2) ^ ((row & 7) << 4))) = (_Float16)v;
}

// dstAct[64][128] = act( srcAct[64][128] @ Gm^T + bias ). Wave tile: 64 rows x
// 32 cols (wave w owns cols [w*32, w*32+32)). B-frags from global, A from LDS.
template <bool SIG>
__device__ __forceinline__ void gemm_flow(const char* srcAct, char* dstAct,
                                          const _Float16* __restrict__ Gm,
                                          const float* __restrict__ bias,
                                          int wave, int lane)
{
    const int l15 = lane & 15, kg = lane >> 4;
    half8 bf[8];
#pragma unroll
    for (int ks = 0; ks < 4; ++ks)
#pragma unroll
        for (int ctl = 0; ctl < 2; ++ctl) {
            const int col = wave * 32 + ctl * 16 + l15;
            bf[ks * 2 + ctl] = *(const half8*)(Gm + col * 128 + ks * 32 + kg * 8);
        }
    f32x4 acc[4][2] = {};
#pragma unroll
    for (int ks = 0; ks < 4; ++ks) {
        const int koff = ks * 64 + kg * 16;  // bytes
#pragma unroll
        for (int rt = 0; rt < 4; ++rt) {
            const int row = rt * 16 + l15;
            half8 a = *(const half8*)(srcAct + row * 256 + (koff ^ ((row & 7) << 4)));
            acc[rt][0] = __builtin_amdgcn_mfma_f32_16x16x32_f16(a, bf[ks * 2 + 0], acc[rt][0], 0, 0, 0);
            acc[rt][1] = __builtin_amdgcn_mfma_f32_16x16x32_f16(a, bf[ks * 2 + 1], acc[rt][1], 0, 0, 0);
        }
    }
#pragma unroll
    for (int rt = 0; rt < 4; ++rt)
#pragma unroll
        for (int ctl = 0; ctl < 2; ++ctl) {
            const int col = wave * 32 + ctl * 16 + l15;
            const float bv = SIG ? bias[col] : 0.f;
#pragma unroll
            for (int j = 0; j < 4; ++j) {
                const int row = rt * 16 + kg * 4 + j;
                float v = acc[rt][ctl][j] + bv;
                if (SIG) v = sigmoidf(v);
                wr_act(dstAct, row, col, v);
            }
        }
}

__global__ __launch_bounds__(256, 4)
void mono_main(const float* __restrict__ x, const float* __restrict__ fy0,
               const float* __restrict__ b0, const float* __restrict__ bM,
               const float* __restrict__ bL,
               const float* __restrict__ b2, const float* __restrict__ b3,
               const _Float16* __restrict__ G, const _Float16* __restrict__ W2h,
               const float* __restrict__ a0x, const float* __restrict__ a0t,
               const float* __restrict__ uLs,
               const float* __restrict__ W1p, const float* __restrict__ b1p,
               const float* __restrict__ W3p,
               float* __restrict__ out)
{
    __shared__ char sm[2 * 16384 + 256];
    char* H = sm;
    char* S = sm + 16384;
    float* thetaS = (float*)(sm + 32768);  // 64 floats

    const int tid  = threadIdx.x;
    const int lane = tid & 63, wave = tid >> 6;
    const int row0 = blockIdx.x * BM;
    const int r4   = tid >> 2, part = tid & 3;   // 64 rows x 4 parts

    // ---- MLP layer 1: h1[64][64] = relu(fy0*W1p + b1p) -> H (fp16 swizzled)
    {
        const float f = fy0[row0 + r4];
#pragma unroll
        for (int q = 0; q < 16; ++q) {
            const int j = part * 16 + q;
            wr_act(H, r4, j, fmaxf(f * W1p[j] + b1p[j], 0.f));
        }
    }
    __syncthreads();

    // ---- MLP layer 2: h2 = relu(h1 @ W2h^T + b2) -> S. Wave tile 64x16.
    {
        const int l15 = lane & 15, kg = lane >> 4;
        half8 bf[2];
#pragma unroll
        for (int ks = 0; ks < 2; ++ks)
            bf[ks] = *(const half8*)(W2h + (wave * 16 + l15) * 64 + ks * 32 + kg * 8);
        f32x4 acc[4] = {};
#pragma unroll
        for (int ks = 0; ks < 2; ++ks) {
            const int koff = ks * 64 + kg * 16;
#pragma unroll
            for (int rt = 0; rt < 4; ++rt) {
                const int row = rt * 16 + l15;
                half8 a = *(const half8*)(H + row * 256 + (koff ^ ((row & 7) << 4)));
                acc[rt] = __builtin_amdgcn_mfma_f32_16x16x32_f16(a, bf[ks], acc[rt], 0, 0, 0);
            }
        }
        const int col = wave * 16 + l15;
        const float bv = (col < 50) ? b2[col] : 0.f;
#pragma unroll
        for (int rt = 0; rt < 4; ++rt)
#pragma unroll
            for (int j = 0; j < 4; ++j)
                wr_act(S, rt * 16 + kg * 4 + j, col, fmaxf(acc[rt][j] + bv, 0.f));
    }
    __syncthreads();

    // ---- MLP layer 3: theta[r] = h2 . W3p + b3 (cols 0..63, pads are 0)
    {
        const int sw = (r4 & 7) << 4;
        float s = 0.f;
#pragma unroll
        for (int v = 0; v < 2; ++v) {
            half8 hv = *(const half8*)(S + r4 * 256 + ((part * 32 + v * 16) ^ sw));
#pragma unroll
            for (int e = 0; e < 8; ++e) s += (float)hv[e] * W3p[part * 16 + v * 8 + e];
        }
        s += __shfl_xor(s, 1);
        s += __shfl_xor(s, 2);
        if (part == 0) thetaS[r4] = s + b3[0];
    }
    __syncthreads();

    // ---- first flow layer (in=2): S = sigmoid(a0x*x + a0t*theta + b0)
    {
        const float xr = x[row0 + r4];
        const float th = thetaS[r4];
#pragma unroll
        for (int q = 0; q < 32; ++q) {
            const int j = part * 32 + q;
            wr_act(S, r4, j, sigmoidf(a0x[j] * xr + a0t[j] * th + b0[j]));
        }
    }
    __syncthreads();

    // ---- flow gemms: H = S @ W0^T; then 6x { S = sig(H@A^T+b); H = S@W^T }
    gemm_flow<false>(S, H, G, nullptr, wave, lane);
    __syncthreads();
#pragma unroll 1
    for (int l = 0; l < 6; ++l) {
        gemm_flow<true>(H, S, G + (1 + 2 * l) * 16384, bM + l * 128, wave, lane);
        __syncthreads();
        gemm_flow<false>(S, H, G + (2 + 2 * l) * 16384, nullptr, wave, lane);
        __syncthreads();
    }

    // ---- last layer: out = sigmoid(H . uLs + bL)
    {
        const int sw = (r4 & 7) << 4;
        float s = 0.f;
#pragma unroll
        for (int v = 0; v < 4; ++v) {
            half8 hv = *(const half8*)(H + r4 * 256 + ((part * 64 + v * 16) ^ sw));
#pragma unroll
            for (int e = 0; e < 8; ++e) s += (float)hv[e] * uLs[part * 32 + v * 8 + e];
        }
        s += __shfl_xor(s, 1);
        s += __shfl_xor(s, 2);
        if (part == 0) out[row0 + r4] = sigmoidf(s + bL[0]);
    }
}

extern "C" void kernel_launch(void* const* d_in, const int* in_sizes, int n_in,
                              void* d_out, int out_size, void* d_ws, size_t ws_size,
                              hipStream_t stream)
{
    const float* x   = (const float*)d_in[0];
    const float* fy0 = (const float*)d_in[1];
    const float* u0  = (const float*)d_in[2];
    const float* w0  = (const float*)d_in[3];
    const float* la0 = (const float*)d_in[4];
    const float* b0  = (const float*)d_in[5];
    const float* uM  = (const float*)d_in[6];
    const float* wM  = (const float*)d_in[7];
    const float* laM = (const float*)d_in[8];
    const float* bM  = (const float*)d_in[9];
    const float* uL  = (const float*)d_in[10];
    // d_in[11] = wL: softmax over [1,1] row == 1.0, no-op
    const float* laL = (const float*)d_in[12];
    const float* bL  = (const float*)d_in[13];
    const float* W1  = (const float*)d_in[14];
    const float* b1  = (const float*)d_in[15];
    const float* W2  = (const float*)d_in[16];
    const float* b2  = (const float*)d_in[17];
    const float* W3  = (const float*)d_in[18];
    const float* b3  = (const float*)d_in[19];
    float* out = (float*)d_out;

    char* ws = (char*)d_ws;
    _Float16* G   = (_Float16*)ws;                        // 13 * 32768 B
    _Float16* W2h = (_Float16*)(ws + 13 * 32768);         // 8192 B
    float* a0x  = (float*)(ws + 13 * 32768 + 8192);
    float* a0t  = a0x + 128;
    float* uLso = a0t + 128;
    float* W1p  = uLso + 128;
    float* b1p  = W1p + 64;
    float* W3p  = b1p + 64;

    prep_kernel<<<1667, 64, 0, stream>>>(u0, w0, la0, uM, wM, laM, uL, laL,
                                         W1, b1, W2, W3,
                                         G, W2h, a0x, a0t, uLso, W1p, b1p, W3p);
    mono_main<<<131072 / BM, 256, 0, stream>>>(x, fy0, b0, bM, bL, b2, b3,
                                               G, W2h, a0x, a0t, uLso,
                                               W1p, b1p, W3p, out);
}

// Round 5
// 165.342 us; speedup vs baseline: 1.7227x; 1.4867x over previous
//
#include <hip/hip_runtime.h>
#include <cstdint>

typedef __attribute__((ext_vector_type(8))) _Float16 half8;
typedef __attribute__((ext_vector_type(2))) _Float16 half2v;
typedef __attribute__((ext_vector_type(16))) float f32x16;
typedef __attribute__((ext_vector_type(4))) float f4;

#define LOG2E 1.44269504088896340f

__device__ __forceinline__ float fast_exp(float x) { return __builtin_amdgcn_exp2f(LOG2E * x); }
__device__ __forceinline__ float sigmoidf(float v) {
    return __builtin_amdgcn_rcpf(1.f + __builtin_amdgcn_exp2f(-LOG2E * v));
}
__device__ __forceinline__ unsigned pk2(float a, float b) {
    half2v h = { (_Float16)a, (_Float16)b };
    return __builtin_bit_cast(unsigned, h);
}
__device__ __forceinline__ void swapl(unsigned& a, unsigned& b) {
    asm volatile("v_permlane32_swap_b32 %0, %1" : "+v"(a), "+v"(b));
}
__device__ __forceinline__ void swaplf(float& a, float& b) {
    asm volatile("v_permlane32_swap_b32 %0, %1" : "+v"(a), "+v"(b));
}
union BU { unsigned u[4]; half8 h; };

// CgF const region layout (f32 indices)
constexpr int A0X = 0, A0T = 128, B0O = 256, BMO = 384, VLO = 1152,
              W1P = 1280, B1P = 1344, B2P = 1408, W3P = 1472, ULSF = 1536, CN = 1664;

// ws byte offsets
constexpr int GOFF  = 0;                 // 6 layers x [Mhi 32768 | Mlo 32768]
constexpr int W2HI  = 6 * 65536;         // 8192
constexpr int W2LO  = W2HI + 8192;       // 8192
constexpr int CGOFF = W2LO + 8192;       // CN*4
constexpr int WFOFF = CGOFF + 8192;      // 7 x 65536 fp32 (W0..W6 softmaxed)
constexpr int AFOFF = WFOFF + 7 * 65536; // 6 x 65536 fp32 (A1..A6 scaled)

// ---------------- prep phase 1: row softmaxes -> fp32 scratch ----------------
__global__ void prep1_kernel(const float* __restrict__ u0, const float* __restrict__ w0,
                             const float* __restrict__ la0, const float* __restrict__ b0,
                             const float* __restrict__ uM, const float* __restrict__ wM,
                             const float* __restrict__ laM, const float* __restrict__ bM,
                             const float* __restrict__ uL, const float* __restrict__ laL,
                             const float* __restrict__ W1, const float* __restrict__ b1,
                             const float* __restrict__ W2, const float* __restrict__ b2,
                             const float* __restrict__ W3,
                             float* __restrict__ Wf, float* __restrict__ Af,
                             _Float16* __restrict__ W2hi, _Float16* __restrict__ W2lo,
                             float* __restrict__ CgF)
{
    const int b = blockIdx.x, lane = threadIdx.x;
    if (b < 1664) {
        const int m = b >> 7, r = b & 127;
        const float* src;
        float scale = 1.f;
        float* dst;
        if (m == 0) {
            src = w0 + r * 128;
            dst = Wf + r * 128;
        } else if (m & 1) {
            int l = (m - 1) >> 1;
            src = uM + (l * 128 + r) * 128;
            scale = fast_exp(laM[l * 128 + r]);
            dst = Af + l * 16384 + r * 128;
        } else {
            int l = (m - 2) >> 1;
            src = wM + (l * 128 + r) * 128;
            dst = Wf + (l + 1) * 16384 + r * 128;
        }
        float v0 = src[lane], v1 = src[lane + 64];
        float mx = fmaxf(v0, v1);
#pragma unroll
        for (int o = 32; o; o >>= 1) mx = fmaxf(mx, __shfl_xor(mx, o));
        float e0 = fast_exp(v0 - mx), e1 = fast_exp(v1 - mx);
        float ssum = e0 + e1;
#pragma unroll
        for (int o = 32; o; o >>= 1) ssum += __shfl_xor(ssum, o);
        float inv = scale / ssum;
        dst[lane]      = e0 * inv;
        dst[lane + 64] = e1 * inv;
    } else if (b == 1664) {
        for (int j = lane; j < 128; j += 64) {
            float q0 = u0[2 * j], q1 = u0[2 * j + 1];
            float mx = fmaxf(q0, q1);
            float e0 = fast_exp(q0 - mx), e1 = fast_exp(q1 - mx);
            float a = fast_exp(la0[j]) / (e0 + e1);
            CgF[A0X + j] = a * e0;
            CgF[A0T + j] = a * e1;
            CgF[B0O + j] = b0[j];
        }
        CgF[W1P + lane] = (lane < 50) ? W1[lane] : 0.f;
        CgF[B1P + lane] = (lane < 50) ? b1[lane] : 0.f;
        CgF[B2P + lane] = (lane < 50) ? b2[lane] : 0.f;
        CgF[W3P + lane] = (lane < 50) ? W3[lane] : 0.f;
        for (int i = lane; i < 768; i += 64) CgF[BMO + i] = bM[i];
    } else if (b == 1665) {
        float v0 = uL[lane], v1 = uL[lane + 64];
        float mx = fmaxf(v0, v1);
#pragma unroll
        for (int o = 32; o; o >>= 1) mx = fmaxf(mx, __shfl_xor(mx, o));
        float e0 = fast_exp(v0 - mx), e1 = fast_exp(v1 - mx);
        float ssum = e0 + e1;
#pragma unroll
        for (int o = 32; o; o >>= 1) ssum += __shfl_xor(ssum, o);
        float aL = fast_exp(laL[0]) / ssum;
        CgF[ULSF + lane]      = e0 * aL;
        CgF[ULSF + 64 + lane] = e1 * aL;
    } else {
        for (int i = lane; i < 4096; i += 64) {
            int r = i >> 6, c = i & 63;
            float v = (r < 50 && c < 50) ? W2[r * 50 + c] : 0.f;
            _Float16 h = (_Float16)v;
            W2hi[i] = h;
            W2lo[i] = (_Float16)(v - (float)h);
        }
    }
}

// ---------------- prep phase 2: fused products M_l = A_{l+1} * W_l, split hi/lo,
// swizzled for LDS; plus vL = W6^T uLs ----------------
__global__ void prep2_kernel(const float* __restrict__ Wf, const float* __restrict__ Af,
                             char* __restrict__ G, float* __restrict__ CgF)
{
    const int b = blockIdx.x, lane = threadIdx.x;
    if (b < 768) {
        const int l = b >> 7, i = b & 127;
        const float* Arow = Af + l * 16384 + i * 128;
        const float* W = Wf + l * 16384;
        float m0 = 0.f, m1 = 0.f;
        for (int k = 0; k < 128; ++k) {
            float a = Arow[k];
            m0 += a * W[k * 128 + lane];
            m1 += a * W[k * 128 + lane + 64];
        }
        char* basehi = G + l * 65536 + i * 256;
        char* baselo = basehi + 32768;
        const int sw = (i & 7) << 4;
        _Float16 h0 = (_Float16)m0, h1 = (_Float16)m1;
        *(_Float16*)(basehi + ((2 * lane) ^ sw))        = h0;
        *(_Float16*)(basehi + ((2 * (lane + 64)) ^ sw)) = h1;
        *(_Float16*)(baselo + ((2 * lane) ^ sw))        = (_Float16)(m0 - (float)h0);
        *(_Float16*)(baselo + ((2 * (lane + 64)) ^ sw)) = (_Float16)(m1 - (float)h1);
    } else {
        const float* W6 = Wf + 6 * 16384;
        float m0 = 0.f, m1 = 0.f;
        for (int i = 0; i < 128; ++i) {
            float u = CgF[ULSF + i];
            m0 += u * W6[i * 128 + lane];
            m1 += u * W6[i * 128 + lane + 64];
        }
        CgF[VLO + lane]      = m0;
        CgF[VLO + 64 + lane] = m1;
    }
}

// ---------------- main ----------------
// 256 blocks x 512 threads (8 waves, 1 block/CU). LDS: 2 x 64KB dbuf of
// [Mhi|Mlo] fp16 swizzled, staged via global_load_lds, prefetched 1 layer ahead.
// Activations register-resident: fp16 B-frags, layer-to-layer via pack+permlane.

__device__ __forceinline__ void stage64(char* ls, const char* gs, int tid) {
#pragma unroll
    for (int i = 0; i < 8; ++i)
        __builtin_amdgcn_global_load_lds(
            (const __attribute__((address_space(1))) unsigned*)(uintptr_t)(gs + tid * 16 + i * 8192),
            (__attribute__((address_space(3))) unsigned*)(uintptr_t)(ls + tid * 16 + i * 8192),
            16, 0, 0);
}

// acc(2 batch-halves) for one ntile -> sigmoid -> B-frags windows 2nt, 2nt+1
__device__ __forceinline__ void epi_nt(const f32x16& a0, const f32x16& a1,
                                       half8& o00, half8& o01, half8& o10, half8& o11,
                                       const float* __restrict__ biasNT, int hi)
{
    f4 bv0 = *(const f4*)(biasNT + 4 * hi);
    f4 bv1 = *(const f4*)(biasNT + 8 + 4 * hi);
    f4 bv2 = *(const f4*)(biasNT + 16 + 4 * hi);
    f4 bv3 = *(const f4*)(biasNT + 24 + 4 * hi);
#pragma unroll
    for (int bt = 0; bt < 2; ++bt) {
        const f32x16& A = bt ? a1 : a0;
        unsigned p00 = pk2(sigmoidf(A[0] + bv0[0]),  sigmoidf(A[1] + bv0[1]));
        unsigned p01 = pk2(sigmoidf(A[2] + bv0[2]),  sigmoidf(A[3] + bv0[3]));
        unsigned p10 = pk2(sigmoidf(A[4] + bv1[0]),  sigmoidf(A[5] + bv1[1]));
        unsigned p11 = pk2(sigmoidf(A[6] + bv1[2]),  sigmoidf(A[7] + bv1[3]));
        unsigned p20 = pk2(sigmoidf(A[8] + bv2[0]),  sigmoidf(A[9] + bv2[1]));
        unsigned p21 = pk2(sigmoidf(A[10] + bv2[2]), sigmoidf(A[11] + bv2[3]));
        unsigned p30 = pk2(sigmoidf(A[12] + bv3[0]), sigmoidf(A[13] + bv3[1]));
        unsigned p31 = pk2(sigmoidf(A[14] + bv3[2]), sigmoidf(A[15] + bv3[3]));
        swapl(p00, p10); swapl(p01, p11);   // window 2nt
        swapl(p20, p30); swapl(p21, p31);   // window 2nt+1
        BU u0; u0.u[0] = p00; u0.u[1] = p01; u0.u[2] = p10; u0.u[3] = p11;
        BU u1; u1.u[0] = p20; u1.u[1] = p21; u1.u[2] = p30; u1.u[3] = p31;
        if (bt == 0) { o00 = u0.h; o01 = u1.h; }
        else         { o10 = u0.h; o11 = u1.h; }
    }
}

// One fused flow layer: Bout = sigmoid( (Mhi+Mlo) * Bin + bias )
__device__ __forceinline__ void do_layer(const char* buf,
                                         const half8 (&Bin)[2][8], half8 (&Bout)[2][8],
                                         const float* __restrict__ biasL,
                                         int l31, int hi)
{
    const int sw = (l31 & 7) << 4;
#pragma unroll
    for (int nt = 0; nt < 4; ++nt) {
        f32x16 a0 = {}, a1 = {};
        const char* rhi = buf + (nt * 32 + l31) * 256;
        const char* rlo = rhi + 32768;
#pragma unroll
        for (int ks = 0; ks < 8; ++ks) {
            const int off = (ks * 32 + hi * 16) ^ sw;
            half8 Ah = *(const half8*)(rhi + off);
            half8 Al = *(const half8*)(rlo + off);
            a0 = __builtin_amdgcn_mfma_f32_32x32x16_f16(Ah, Bin[0][ks], a0, 0, 0, 0);
            a1 = __builtin_amdgcn_mfma_f32_32x32x16_f16(Ah, Bin[1][ks], a1, 0, 0, 0);
            a0 = __builtin_amdgcn_mfma_f32_32x32x16_f16(Al, Bin[0][ks], a0, 0, 0, 0);
            a1 = __builtin_amdgcn_mfma_f32_32x32x16_f16(Al, Bin[1][ks], a1, 0, 0, 0);
        }
        epi_nt(a0, a1, Bout[0][2 * nt], Bout[0][2 * nt + 1],
               Bout[1][2 * nt], Bout[1][2 * nt + 1], biasL + 32 * nt, hi);
    }
}

__global__ __launch_bounds__(512, 2)
void mono_main(const float* __restrict__ x, const float* __restrict__ fy0,
               const char* __restrict__ G,
               const _Float16* __restrict__ W2hi, const _Float16* __restrict__ W2lo,
               const float* __restrict__ CgF, const float* __restrict__ b3g,
               const float* __restrict__ bLg, float* __restrict__ out)
{
    extern __shared__ __align__(16) char sm[];   // 131072: buf0 | buf1
    char* buf0 = sm;
    char* buf1 = sm + 65536;

    const int tid = threadIdx.x;
    const int lane = tid & 63, wave = tid >> 6;
    const int l31 = lane & 31, hi = lane >> 5;
    const int row0 = blockIdx.x * 512 + wave * 64;

    stage64(buf0, G, tid);   // layer 0 weights; overlaps with MLP below
    const float b3s = b3g[0], bLs = bLg[0];

    // ---- MLP layer 1: h1 B-frags (col=batch, k=feature) ----
    float fy[2] = { fy0[row0 + l31], fy0[row0 + 32 + l31] };
    half8 Bm[2][4];
#pragma unroll
    for (int ks = 0; ks < 4; ++ks) {
        f4 w1a = *(const f4*)(CgF + W1P + 16 * ks + 8 * hi);
        f4 w1b = *(const f4*)(CgF + W1P + 16 * ks + 8 * hi + 4);
        f4 b1a = *(const f4*)(CgF + B1P + 16 * ks + 8 * hi);
        f4 b1b = *(const f4*)(CgF + B1P + 16 * ks + 8 * hi + 4);
#pragma unroll
        for (int bt = 0; bt < 2; ++bt) {
            BU u;
            u.u[0] = pk2(fmaxf(fy[bt] * w1a[0] + b1a[0], 0.f), fmaxf(fy[bt] * w1a[1] + b1a[1], 0.f));
            u.u[1] = pk2(fmaxf(fy[bt] * w1a[2] + b1a[2], 0.f), fmaxf(fy[bt] * w1a[3] + b1a[3], 0.f));
            u.u[2] = pk2(fmaxf(fy[bt] * w1b[0] + b1b[0], 0.f), fmaxf(fy[bt] * w1b[1] + b1b[1], 0.f));
            u.u[3] = pk2(fmaxf(fy[bt] * w1b[2] + b1b[2], 0.f), fmaxf(fy[bt] * w1b[3] + b1b[3], 0.f));
            Bm[bt][ks] = u.h;
        }
    }

    // ---- MLP layer 2 (padded 64x64, W2 split hi+lo) ----
    f32x16 a00 = {}, a01 = {}, a10 = {}, a11 = {};
#pragma unroll
    for (int nt = 0; nt < 2; ++nt)
#pragma unroll
        for (int ks = 0; ks < 4; ++ks) {
            half8 Ah = *(const half8*)(W2hi + (nt * 32 + l31) * 64 + ks * 16 + hi * 8);
            half8 Al = *(const half8*)(W2lo + (nt * 32 + l31) * 64 + ks * 16 + hi * 8);
            if (nt == 0) {
                a00 = __builtin_amdgcn_mfma_f32_32x32x16_f16(Ah, Bm[0][ks], a00, 0, 0, 0);
                a10 = __builtin_amdgcn_mfma_f32_32x32x16_f16(Ah, Bm[1][ks], a10, 0, 0, 0);
                a00 = __builtin_amdgcn_mfma_f32_32x32x16_f16(Al, Bm[0][ks], a00, 0, 0, 0);
                a10 = __builtin_amdgcn_mfma_f32_32x32x16_f16(Al, Bm[1][ks], a10, 0, 0, 0);
            } else {
                a01 = __builtin_amdgcn_mfma_f32_32x32x16_f16(Ah, Bm[0][ks], a01, 0, 0, 0);
                a11 = __builtin_amdgcn_mfma_f32_32x32x16_f16(Ah, Bm[1][ks], a11, 0, 0, 0);
                a01 = __builtin_amdgcn_mfma_f32_32x32x16_f16(Al, Bm[0][ks], a01, 0, 0, 0);
                a11 = __builtin_amdgcn_mfma_f32_32x32x16_f16(Al, Bm[1][ks], a11, 0, 0, 0);
            }
        }

    // ---- MLP layer 3: theta ----
    float tp0 = 0.f, tp1 = 0.f;
#pragma unroll
    for (int nt = 0; nt < 2; ++nt)
#pragma unroll
        for (int g = 0; g < 4; ++g) {
            f4 w3 = *(const f4*)(CgF + W3P + 32 * nt + 8 * g + 4 * hi);
            f4 b2v = *(const f4*)(CgF + B2P + 32 * nt + 8 * g + 4 * hi);
            const f32x16& A0 = nt ? a01 : a00;
            const f32x16& A1 = nt ? a11 : a10;
#pragma unroll
            for (int e = 0; e < 4; ++e) {
                tp0 += w3[e] * fmaxf(A0[4 * g + e] + b2v[e], 0.f);
                tp1 += w3[e] * fmaxf(A1[4 * g + e] + b2v[e], 0.f);
            }
        }
    swaplf(tp0, tp1);
    float th = tp0 + tp1 + b3s;
    float t0 = th, t1 = th;
    swaplf(t0, t1);

    // ---- first flow layer (in=2): S0 B-frags (fp32 math) ----
    float xr[2] = { x[row0 + l31], x[row0 + 32 + l31] };
    float thv[2] = { t0, t1 };
    half8 Bq[2][8], Bp[2][8];
#pragma unroll
    for (int ks = 0; ks < 8; ++ks) {
        f4 axa = *(const f4*)(CgF + A0X + 16 * ks + 8 * hi);
        f4 axb = *(const f4*)(CgF + A0X + 16 * ks + 8 * hi + 4);
        f4 ata = *(const f4*)(CgF + A0T + 16 * ks + 8 * hi);
        f4 atb = *(const f4*)(CgF + A0T + 16 * ks + 8 * hi + 4);
        f4 b0a = *(const f4*)(CgF + B0O + 16 * ks + 8 * hi);
        f4 b0b = *(const f4*)(CgF + B0O + 16 * ks + 8 * hi + 4);
#pragma unroll
        for (int bt = 0; bt < 2; ++bt) {
            BU u;
            u.u[0] = pk2(sigmoidf(axa[0] * xr[bt] + ata[0] * thv[bt] + b0a[0]),
                         sigmoidf(axa[1] * xr[bt] + ata[1] * thv[bt] + b0a[1]));
            u.u[1] = pk2(sigmoidf(axa[2] * xr[bt] + ata[2] * thv[bt] + b0a[2]),
                         sigmoidf(axa[3] * xr[bt] + ata[3] * thv[bt] + b0a[3]));
            u.u[2] = pk2(sigmoidf(axb[0] * xr[bt] + atb[0] * thv[bt] + b0b[0]),
                         sigmoidf(axb[1] * xr[bt] + atb[1] * thv[bt] + b0b[1]));
            u.u[3] = pk2(sigmoidf(axb[2] * xr[bt] + atb[2] * thv[bt] + b0b[2]),
                         sigmoidf(axb[3] * xr[bt] + atb[3] * thv[bt] + b0b[3]));
            Bq[bt][ks] = u.h;
        }
    }
    __syncthreads();   // layer-0 weights staged

    // ---- 6 fused flow layers, dbuf ping-pong, prefetch 1 ahead ----
    stage64(buf1, G + 1 * 65536, tid);
    do_layer(buf0, Bq, Bp, CgF + BMO + 0 * 128, l31, hi);
    __syncthreads();
    stage64(buf0, G + 2 * 65536, tid);
    do_layer(buf1, Bp, Bq, CgF + BMO + 1 * 128, l31, hi);
    __syncthreads();
    stage64(buf1, G + 3 * 65536, tid);
    do_layer(buf0, Bq, Bp, CgF + BMO + 2 * 128, l31, hi);
    __syncthreads();
    stage64(buf0, G + 4 * 65536, tid);
    do_layer(buf1, Bp, Bq, CgF + BMO + 3 * 128, l31, hi);
    __syncthreads();
    stage64(buf1, G + 5 * 65536, tid);
    do_layer(buf0, Bq, Bp, CgF + BMO + 4 * 128, l31, hi);
    __syncthreads();
    do_layer(buf1, Bp, Bq, CgF + BMO + 5 * 128, l31, hi);   // S6 -> Bq

    // ---- final: out = sigmoid( vL . S6 + bL ), fp32 dot ----
    float d0 = 0.f, d1 = 0.f;
#pragma unroll
    for (int ks = 0; ks < 8; ++ks) {
        f4 va = *(const f4*)(CgF + VLO + 16 * ks + 8 * hi);
        f4 vb = *(const f4*)(CgF + VLO + 16 * ks + 8 * hi + 4);
        half8 s0 = Bq[0][ks], s1 = Bq[1][ks];
#pragma unroll
        for (int e = 0; e < 4; ++e) {
            d0 += va[e] * (float)s0[e] + vb[e] * (float)s0[e + 4];
            d1 += va[e] * (float)s1[e] + vb[e] * (float)s1[e + 4];
        }
    }
    swaplf(d0, d1);
    out[row0 + lane] = sigmoidf(d0 + d1 + bLs);
}

extern "C" void kernel_launch(void* const* d_in, const int* in_sizes, int n_in,
                              void* d_out, int out_size, void* d_ws, size_t ws_size,
                              hipStream_t stream)
{
    const float* x   = (const float*)d_in[0];
    const float* fy0 = (const float*)d_in[1];
    const float* u0  = (const float*)d_in[2];
    const float* w0  = (const float*)d_in[3];
    const float* la0 = (const float*)d_in[4];
    const float* b0  = (const float*)d_in[5];
    const float* uM  = (const float*)d_in[6];
    const float* wM  = (const float*)d_in[7];
    const float* laM = (const float*)d_in[8];
    const float* bM  = (const float*)d_in[9];
    const float* uL  = (const float*)d_in[10];
    // d_in[11] = wL: softmax over [1,1] == 1.0
    const float* laL = (const float*)d_in[12];
    const float* bL  = (const float*)d_in[13];
    const float* W1  = (const float*)d_in[14];
    const float* b1  = (const float*)d_in[15];
    const float* W2  = (const float*)d_in[16];
    const float* b2  = (const float*)d_in[17];
    const float* W3  = (const float*)d_in[18];
    const float* b3  = (const float*)d_in[19];
    float* out = (float*)d_out;

    char* ws = (char*)d_ws;
    char*     Gz   = ws + GOFF;
    _Float16* W2hi = (_Float16*)(ws + W2HI);
    _Float16* W2lo = (_Float16*)(ws + W2LO);
    float*    CgF  = (float*)(ws + CGOFF);
    float*    Wf   = (float*)(ws + WFOFF);
    float*    Af   = (float*)(ws + AFOFF);

    prep1_kernel<<<1667, 64, 0, stream>>>(u0, w0, la0, b0, uM, wM, laM, bM,
                                          uL, laL, W1, b1, W2, b2, W3,
                                          Wf, Af, W2hi, W2lo, CgF);
    prep2_kernel<<<769, 64, 0, stream>>>(Wf, Af, Gz, CgF);

    static bool attr_set = false;
    if (!attr_set) {
        hipFuncSetAttribute((const void*)mono_main,
                            hipFuncAttributeMaxDynamicSharedMemorySize, 131072);
        attr_set = true;
    }
    mono_main<<<256, 512, 131072, stream>>>(x, fy0, Gz, W2hi, W2lo, CgF, b3, bL, out);
}

// Round 6
// 154.593 us; speedup vs baseline: 1.8425x; 1.0695x over previous
//
#include <hip/hip_runtime.h>
#include <cstdint>

typedef __attribute__((ext_vector_type(8))) _Float16 half8;
typedef __attribute__((ext_vector_type(2))) _Float16 half2v;
typedef __attribute__((ext_vector_type(16))) float f32x16;
typedef __attribute__((ext_vector_type(4))) float f4;

#define LOG2E 1.44269504088896340f
#define KNL  (-1.44269504088896340f)

__device__ __forceinline__ float fast_exp(float x) { return __builtin_amdgcn_exp2f(LOG2E * x); }
__device__ __forceinline__ float sigmoidf(float v) {
    return __builtin_amdgcn_rcpf(1.f + __builtin_amdgcn_exp2f(KNL * v));
}
// sigmoid(v + b) with nb = KNL*b precomputed: one FMA instead of add+mul
__device__ __forceinline__ float sigx(float v, float nb) {
    return __builtin_amdgcn_rcpf(1.f + __builtin_amdgcn_exp2f(fmaf(v, KNL, nb)));
}
__device__ __forceinline__ unsigned pk2(float a, float b) {
    half2v h = { (_Float16)a, (_Float16)b };
    return __builtin_bit_cast(unsigned, h);
}
__device__ __forceinline__ void swapl(unsigned& a, unsigned& b) {
    asm volatile("v_permlane32_swap_b32 %0, %1" : "+v"(a), "+v"(b));
}
__device__ __forceinline__ void swaplf(float& a, float& b) {
    asm volatile("v_permlane32_swap_b32 %0, %1" : "+v"(a), "+v"(b));
}
union BU { unsigned u[4]; half8 h; };

// CgF const region layout (f32 indices). BMO holds KNL*bM (pre-scaled).
constexpr int A0X = 0, A0T = 128, B0O = 256, BMO = 384, VLO = 1152,
              W1P = 1280, B1P = 1344, B2P = 1408, W3P = 1472, CN = 1536;

// ws byte offsets
constexpr int GOFF  = 0;                 // 6 layers x [Mhi 32768 | Mlo 32768]
constexpr int W2HI  = 6 * 65536;         // 8192
constexpr int W2LO  = W2HI + 8192;       // 8192
constexpr int CGOFF = W2LO + 8192;       // CN*4

// ---------------- fused prep: 25 blocks x 256 threads ----------------
// Blocks 0..23 (l = b>>2, q = b&3): rows [32q,32q+32) of M_l = A_{l+1}*W_l,
// fp32 product, split fp16 hi/lo, written swizzled for mono's ds_read layout.
// Block 24: vL = W6^T uLs, first-layer consts, MLP consts, W2 hi/lo, KNL*bM.
__global__ __launch_bounds__(256)
void prep_kernel(const float* __restrict__ u0, const float* __restrict__ w0,
                 const float* __restrict__ la0, const float* __restrict__ b0,
                 const float* __restrict__ uM, const float* __restrict__ wM,
                 const float* __restrict__ laM, const float* __restrict__ bM,
                 const float* __restrict__ uL, const float* __restrict__ laL,
                 const float* __restrict__ W1, const float* __restrict__ b1,
                 const float* __restrict__ W2, const float* __restrict__ b2,
                 const float* __restrict__ W3,
                 char* __restrict__ G, _Float16* __restrict__ W2hi,
                 _Float16* __restrict__ W2lo, float* __restrict__ CgF)
{
    __shared__ float Wl[128 * 136];   // softmaxed W, row pad 136 (16B-aligned rows)
    __shared__ float Al[32 * 132];    // scaled-softmaxed A rows, pad 132
    __shared__ float uls[128];

    const int tid = threadIdx.x, b = blockIdx.x;
    const bool mblk = (b < 24);
    const int l = mblk ? (b >> 2) : 6;

    // ---- step 1: row-softmax W_l into LDS (all blocks) ----
    {
        const float* Wsrc = (l == 0) ? w0 : wM + (l - 1) * 16384;
        const int r = tid >> 1, h = tid & 1;   // 2 threads per row, 64 elems each
        const float* rp = Wsrc + r * 128 + h * 64;
        f4 buf[16];
#pragma unroll
        for (int v = 0; v < 16; ++v) buf[v] = *(const f4*)(rp + 4 * v);
        float mx = -1e30f;
#pragma unroll
        for (int v = 0; v < 16; ++v)
#pragma unroll
            for (int e = 0; e < 4; ++e) mx = fmaxf(mx, buf[v][e]);
        mx = fmaxf(mx, __shfl_xor(mx, 1));
        float s = 0.f;
#pragma unroll
        for (int v = 0; v < 16; ++v)
#pragma unroll
            for (int e = 0; e < 4; ++e) { buf[v][e] = fast_exp(buf[v][e] - mx); s += buf[v][e]; }
        s += __shfl_xor(s, 1);
        float inv = 1.f / s;
#pragma unroll
        for (int v = 0; v < 16; ++v)
            *(f4*)(&Wl[r * 136 + h * 64 + 4 * v]) = buf[v] * inv;
    }

    if (mblk) {
        const int q = b & 3;
        const int rl = tid >> 3, part = tid & 7;  // 32 rows, 8 threads/row
        const int gi = q * 32 + rl;               // global output row
        // ---- step 2: A row gi = exp(laM)*softmax(uM row) ----
        {
            const float* up = uM + (l * 128 + gi) * 128 + part * 16;
            f4 ub[4];
#pragma unroll
            for (int v = 0; v < 4; ++v) ub[v] = *(const f4*)(up + 4 * v);
            float mx = -1e30f;
#pragma unroll
            for (int v = 0; v < 4; ++v)
#pragma unroll
                for (int e = 0; e < 4; ++e) mx = fmaxf(mx, ub[v][e]);
#pragma unroll
            for (int o = 1; o < 8; o <<= 1) mx = fmaxf(mx, __shfl_xor(mx, o));
            float s = 0.f;
#pragma unroll
            for (int v = 0; v < 4; ++v)
#pragma unroll
                for (int e = 0; e < 4; ++e) { ub[v][e] = fast_exp(ub[v][e] - mx); s += ub[v][e]; }
#pragma unroll
            for (int o = 1; o < 8; o <<= 1) s += __shfl_xor(s, o);
            float sc = fast_exp(laM[l * 128 + gi]) / s;
#pragma unroll
            for (int v = 0; v < 4; ++v)
                *(f4*)(&Al[rl * 132 + part * 16 + 4 * v]) = ub[v] * sc;
        }
        __syncthreads();
        // ---- step 3: M rows = A @ W (fp32). Thread: row rl, cols j0+32g+e ----
        const int j0 = (tid & 7) * 4;
        f4 acc[4] = {};
        for (int k = 0; k < 128; ++k) {
            float a = Al[rl * 132 + k];
#pragma unroll
            for (int g = 0; g < 4; ++g)
                acc[g] += a * *(const f4*)(&Wl[k * 136 + j0 + 32 * g]);
        }
        // ---- step 4: split hi/lo, write swizzled ----
        char* basehi = G + l * 65536 + gi * 256;
        char* baselo = basehi + 32768;
        const int sw = (gi & 7) << 4;
#pragma unroll
        for (int g = 0; g < 4; ++g)
#pragma unroll
            for (int e = 0; e < 4; ++e) {
                const int j = j0 + 32 * g + e;
                float m = acc[g][e];
                _Float16 hh = (_Float16)m;
                *(_Float16*)(basehi + ((2 * j) ^ sw)) = hh;
                *(_Float16*)(baselo + ((2 * j) ^ sw)) = (_Float16)(m - (float)hh);
            }
    } else {
        // ---- misc block: uls (wave 0), then vL from LDS W6; consts ----
        if (tid < 64) {
            float v0 = uL[tid], v1 = uL[tid + 64];
            float mx = fmaxf(v0, v1);
#pragma unroll
            for (int o = 32; o; o >>= 1) mx = fmaxf(mx, __shfl_xor(mx, o));
            float e0 = fast_exp(v0 - mx), e1 = fast_exp(v1 - mx);
            float ssum = e0 + e1;
#pragma unroll
            for (int o = 32; o; o >>= 1) ssum += __shfl_xor(ssum, o);
            float aL = fast_exp(laL[0]) / ssum;
            uls[tid]      = e0 * aL;
            uls[tid + 64] = e1 * aL;
        }
        __syncthreads();
        if (tid < 128) {
            float s = 0.f;
            for (int k = 0; k < 128; ++k) s += uls[k] * Wl[k * 136 + tid];
            CgF[VLO + tid] = s;
        }
        if (tid < 128) {
            const int j = tid;
            float q0 = u0[2 * j], q1 = u0[2 * j + 1];
            float mx = fmaxf(q0, q1);
            float e0 = fast_exp(q0 - mx), e1 = fast_exp(q1 - mx);
            float a = fast_exp(la0[j]) / (e0 + e1);
            CgF[A0X + j] = a * e0;
            CgF[A0T + j] = a * e1;
            CgF[B0O + j] = b0[j];
        } else if (tid < 192) {
            const int t = tid - 128;
            CgF[W1P + t] = (t < 50) ? W1[t] : 0.f;
            CgF[B1P + t] = (t < 50) ? b1[t] : 0.f;
            CgF[B2P + t] = (t < 50) ? b2[t] : 0.f;
            CgF[W3P + t] = (t < 50) ? W3[t] : 0.f;
        }
        for (int i = tid; i < 768; i += 256) CgF[BMO + i] = KNL * bM[i];
        for (int i = tid; i < 4096; i += 256) {
            int r = i >> 6, c = i & 63;
            float v = (r < 50 && c < 50) ? W2[r * 50 + c] : 0.f;
            _Float16 h = (_Float16)v;
            W2hi[i] = h;
            W2lo[i] = (_Float16)(v - (float)h);
        }
    }
}

// ---------------- main ----------------
// 256 blocks x 512 threads (8 waves, 1 block/CU). LDS: 2 x 64KB dbuf of
// [Mhi|Mlo] fp16 swizzled, staged via global_load_lds, prefetched 1 layer ahead.
// Activations register-resident: fp16 B-frags, layer-to-layer via pack+permlane.

__device__ __forceinline__ void stage64(char* ls, const char* gs, int tid) {
#pragma unroll
    for (int i = 0; i < 8; ++i)
        __builtin_amdgcn_global_load_lds(
            (const __attribute__((address_space(1))) unsigned*)(uintptr_t)(gs + tid * 16 + i * 8192),
            (__attribute__((address_space(3))) unsigned*)(uintptr_t)(ls + tid * 16 + i * 8192),
            16, 0, 0);
}

// acc(2 batch-halves) for one ntile -> sigmoid -> B-frags windows 2nt, 2nt+1.
// biasNT points at KNL-prescaled biases.
__device__ __forceinline__ void epi_nt(const f32x16& a0, const f32x16& a1,
                                       half8& o00, half8& o01, half8& o10, half8& o11,
                                       const float* __restrict__ biasNT, int hi)
{
    f4 bv0 = *(const f4*)(biasNT + 4 * hi);
    f4 bv1 = *(const f4*)(biasNT + 8 + 4 * hi);
    f4 bv2 = *(const f4*)(biasNT + 16 + 4 * hi);
    f4 bv3 = *(const f4*)(biasNT + 24 + 4 * hi);
#pragma unroll
    for (int bt = 0; bt < 2; ++bt) {
        const f32x16& A = bt ? a1 : a0;
        unsigned p00 = pk2(sigx(A[0], bv0[0]),  sigx(A[1], bv0[1]));
        unsigned p01 = pk2(sigx(A[2], bv0[2]),  sigx(A[3], bv0[3]));
        unsigned p10 = pk2(sigx(A[4], bv1[0]),  sigx(A[5], bv1[1]));
        unsigned p11 = pk2(sigx(A[6], bv1[2]),  sigx(A[7], bv1[3]));
        unsigned p20 = pk2(sigx(A[8], bv2[0]),  sigx(A[9], bv2[1]));
        unsigned p21 = pk2(sigx(A[10], bv2[2]), sigx(A[11], bv2[3]));
        unsigned p30 = pk2(sigx(A[12], bv3[0]), sigx(A[13], bv3[1]));
        unsigned p31 = pk2(sigx(A[14], bv3[2]), sigx(A[15], bv3[3]));
        swapl(p00, p10); swapl(p01, p11);   // window 2nt
        swapl(p20, p30); swapl(p21, p31);   // window 2nt+1
        BU u0; u0.u[0] = p00; u0.u[1] = p01; u0.u[2] = p10; u0.u[3] = p11;
        BU u1; u1.u[0] = p20; u1.u[1] = p21; u1.u[2] = p30; u1.u[3] = p31;
        if (bt == 0) { o00 = u0.h; o01 = u1.h; }
        else         { o10 = u0.h; o11 = u1.h; }
    }
}

// One fused flow layer: Bout = sigmoid( (Mhi+Mlo) * Bin + bias )
__device__ __forceinline__ void do_layer(const char* buf,
                                         const half8 (&Bin)[2][8], half8 (&Bout)[2][8],
                                         const float* __restrict__ biasL,
                                         int l31, int hi)
{
    const int sw = (l31 & 7) << 4;
#pragma unroll
    for (int nt = 0; nt < 4; ++nt) {
        f32x16 a0 = {}, a1 = {};
        const char* rhi = buf + (nt * 32 + l31) * 256;
        const char* rlo = rhi + 32768;
#pragma unroll
        for (int ks = 0; ks < 8; ++ks) {
            const int off = (ks * 32 + hi * 16) ^ sw;
            half8 Ah = *(const half8*)(rhi + off);
            half8 Al = *(const half8*)(rlo + off);
            a0 = __builtin_amdgcn_mfma_f32_32x32x16_f16(Ah, Bin[0][ks], a0, 0, 0, 0);
            a1 = __builtin_amdgcn_mfma_f32_32x32x16_f16(Ah, Bin[1][ks], a1, 0, 0, 0);
            a0 = __builtin_amdgcn_mfma_f32_32x32x16_f16(Al, Bin[0][ks], a0, 0, 0, 0);
            a1 = __builtin_amdgcn_mfma_f32_32x32x16_f16(Al, Bin[1][ks], a1, 0, 0, 0);
        }
        epi_nt(a0, a1, Bout[0][2 * nt], Bout[0][2 * nt + 1],
               Bout[1][2 * nt], Bout[1][2 * nt + 1], biasL + 32 * nt, hi);
    }
}

__global__ __launch_bounds__(512, 2)
void mono_main(const float* __restrict__ x, const float* __restrict__ fy0,
               const char* __restrict__ G,
               const _Float16* __restrict__ W2hi, const _Float16* __restrict__ W2lo,
               const float* __restrict__ CgF, const float* __restrict__ b3g,
               const float* __restrict__ bLg, float* __restrict__ out)
{
    extern __shared__ __align__(16) char sm[];   // 131072: buf0 | buf1
    char* buf0 = sm;
    char* buf1 = sm + 65536;

    const int tid = threadIdx.x;
    const int lane = tid & 63, wave = tid >> 6;
    const int l31 = lane & 31, hi = lane >> 5;
    const int row0 = blockIdx.x * 512 + wave * 64;

    stage64(buf0, G, tid);   // layer 0 weights; overlaps with MLP below
    const float b3s = b3g[0], bLs = bLg[0];

    // ---- MLP layer 1: h1 B-frags (col=batch, k=feature) ----
    float fy[2] = { fy0[row0 + l31], fy0[row0 + 32 + l31] };
    half8 Bm[2][4];
#pragma unroll
    for (int ks = 0; ks < 4; ++ks) {
        f4 w1a = *(const f4*)(CgF + W1P + 16 * ks + 8 * hi);
        f4 w1b = *(const f4*)(CgF + W1P + 16 * ks + 8 * hi + 4);
        f4 b1a = *(const f4*)(CgF + B1P + 16 * ks + 8 * hi);
        f4 b1b = *(const f4*)(CgF + B1P + 16 * ks + 8 * hi + 4);
#pragma unroll
        for (int bt = 0; bt < 2; ++bt) {
            BU u;
            u.u[0] = pk2(fmaxf(fy[bt] * w1a[0] + b1a[0], 0.f), fmaxf(fy[bt] * w1a[1] + b1a[1], 0.f));
            u.u[1] = pk2(fmaxf(fy[bt] * w1a[2] + b1a[2], 0.f), fmaxf(fy[bt] * w1a[3] + b1a[3], 0.f));
            u.u[2] = pk2(fmaxf(fy[bt] * w1b[0] + b1b[0], 0.f), fmaxf(fy[bt] * w1b[1] + b1b[1], 0.f));
            u.u[3] = pk2(fmaxf(fy[bt] * w1b[2] + b1b[2], 0.f), fmaxf(fy[bt] * w1b[3] + b1b[3], 0.f));
            Bm[bt][ks] = u.h;
        }
    }

    // ---- MLP layer 2 (padded 64x64, W2 split hi+lo) ----
    f32x16 a00 = {}, a01 = {}, a10 = {}, a11 = {};
#pragma unroll
    for (int nt = 0; nt < 2; ++nt)
#pragma unroll
        for (int ks = 0; ks < 4; ++ks) {
            half8 Ah = *(const half8*)(W2hi + (nt * 32 + l31) * 64 + ks * 16 + hi * 8);
            half8 Al = *(const half8*)(W2lo + (nt * 32 + l31) * 64 + ks * 16 + hi * 8);
            if (nt == 0) {
                a00 = __builtin_amdgcn_mfma_f32_32x32x16_f16(Ah, Bm[0][ks], a00, 0, 0, 0);
                a10 = __builtin_amdgcn_mfma_f32_32x32x16_f16(Ah, Bm[1][ks], a10, 0, 0, 0);
                a00 = __builtin_amdgcn_mfma_f32_32x32x16_f16(Al, Bm[0][ks], a00, 0, 0, 0);
                a10 = __builtin_amdgcn_mfma_f32_32x32x16_f16(Al, Bm[1][ks], a10, 0, 0, 0);
            } else {
                a01 = __builtin_amdgcn_mfma_f32_32x32x16_f16(Ah, Bm[0][ks], a01, 0, 0, 0);
                a11 = __builtin_amdgcn_mfma_f32_32x32x16_f16(Ah, Bm[1][ks], a11, 0, 0, 0);
                a01 = __builtin_amdgcn_mfma_f32_32x32x16_f16(Al, Bm[0][ks], a01, 0, 0, 0);
                a11 = __builtin_amdgcn_mfma_f32_32x32x16_f16(Al, Bm[1][ks], a11, 0, 0, 0);
            }
        }

    // ---- MLP layer 3: theta ----
    float tp0 = 0.f, tp1 = 0.f;
#pragma unroll
    for (int nt = 0; nt < 2; ++nt)
#pragma unroll
        for (int g = 0; g < 4; ++g) {
            f4 w3 = *(const f4*)(CgF + W3P + 32 * nt + 8 * g + 4 * hi);
            f4 b2v = *(const f4*)(CgF + B2P + 32 * nt + 8 * g + 4 * hi);
            const f32x16& A0 = nt ? a01 : a00;
            const f32x16& A1 = nt ? a11 : a10;
#pragma unroll
            for (int e = 0; e < 4; ++e) {
                tp0 += w3[e] * fmaxf(A0[4 * g + e] + b2v[e], 0.f);
                tp1 += w3[e] * fmaxf(A1[4 * g + e] + b2v[e], 0.f);
            }
        }
    swaplf(tp0, tp1);
    float th = tp0 + tp1 + b3s;
    float t0 = th, t1 = th;
    swaplf(t0, t1);

    // ---- first flow layer (in=2): S0 B-frags (fp32 math) ----
    float xr[2] = { x[row0 + l31], x[row0 + 32 + l31] };
    float thv[2] = { t0, t1 };
    half8 Bq[2][8], Bp[2][8];
#pragma unroll
    for (int ks = 0; ks < 8; ++ks) {
        f4 axa = *(const f4*)(CgF + A0X + 16 * ks + 8 * hi);
        f4 axb = *(const f4*)(CgF + A0X + 16 * ks + 8 * hi + 4);
        f4 ata = *(const f4*)(CgF + A0T + 16 * ks + 8 * hi);
        f4 atb = *(const f4*)(CgF + A0T + 16 * ks + 8 * hi + 4);
        f4 b0a = *(const f4*)(CgF + B0O + 16 * ks + 8 * hi);
        f4 b0b = *(const f4*)(CgF + B0O + 16 * ks + 8 * hi + 4);
#pragma unroll
        for (int bt = 0; bt < 2; ++bt) {
            BU u;
            u.u[0] = pk2(sigmoidf(axa[0] * xr[bt] + ata[0] * thv[bt] + b0a[0]),
                         sigmoidf(axa[1] * xr[bt] + ata[1] * thv[bt] + b0a[1]));
            u.u[1] = pk2(sigmoidf(axa[2] * xr[bt] + ata[2] * thv[bt] + b0a[2]),
                         sigmoidf(axa[3] * xr[bt] + ata[3] * thv[bt] + b0a[3]));
            u.u[2] = pk2(sigmoidf(axb[0] * xr[bt] + atb[0] * thv[bt] + b0b[0]),
                         sigmoidf(axb[1] * xr[bt] + atb[1] * thv[bt] + b0b[1]));
            u.u[3] = pk2(sigmoidf(axb[2] * xr[bt] + atb[2] * thv[bt] + b0b[2]),
                         sigmoidf(axb[3] * xr[bt] + atb[3] * thv[bt] + b0b[3]));
            Bq[bt][ks] = u.h;
        }
    }
    __syncthreads();   // layer-0 weights staged

    // ---- 6 fused flow layers, dbuf ping-pong, prefetch 1 ahead ----
    stage64(buf1, G + 1 * 65536, tid);
    do_layer(buf0, Bq, Bp, CgF + BMO + 0 * 128, l31, hi);
    __syncthreads();
    stage64(buf0, G + 2 * 65536, tid);
    do_layer(buf1, Bp, Bq, CgF + BMO + 1 * 128, l31, hi);
    __syncthreads();
    stage64(buf1, G + 3 * 65536, tid);
    do_layer(buf0, Bq, Bp, CgF + BMO + 2 * 128, l31, hi);
    __syncthreads();
    stage64(buf0, G + 4 * 65536, tid);
    do_layer(buf1, Bp, Bq, CgF + BMO + 3 * 128, l31, hi);
    __syncthreads();
    stage64(buf1, G + 5 * 65536, tid);
    do_layer(buf0, Bq, Bp, CgF + BMO + 4 * 128, l31, hi);
    __syncthreads();
    do_layer(buf1, Bp, Bq, CgF + BMO + 5 * 128, l31, hi);   // S6 -> Bq

    // ---- final: out = sigmoid( vL . S6 + bL ), fp32 dot ----
    float d0 = 0.f, d1 = 0.f;
#pragma unroll
    for (int ks = 0; ks < 8; ++ks) {
        f4 va = *(const f4*)(CgF + VLO + 16 * ks + 8 * hi);
        f4 vb = *(const f4*)(CgF + VLO + 16 * ks + 8 * hi + 4);
        half8 s0 = Bq[0][ks], s1 = Bq[1][ks];
#pragma unroll
        for (int e = 0; e < 4; ++e) {
            d0 += va[e] * (float)s0[e] + vb[e] * (float)s0[e + 4];
            d1 += va[e] * (float)s1[e] + vb[e] * (float)s1[e + 4];
        }
    }
    swaplf(d0, d1);
    out[row0 + lane] = sigmoidf(d0 + d1 + bLs);
}

extern "C" void kernel_launch(void* const* d_in, const int* in_sizes, int n_in,
                              void* d_out, int out_size, void* d_ws, size_t ws_size,
                              hipStream_t stream)
{
    const float* x   = (const float*)d_in[0];
    const float* fy0 = (const float*)d_in[1];
    const float* u0  = (const float*)d_in[2];
    const float* w0  = (const float*)d_in[3];
    const float* la0 = (const float*)d_in[4];
    const float* b0  = (const float*)d_in[5];
    const float* uM  = (const float*)d_in[6];
    const float* wM  = (const float*)d_in[7];
    const float* laM = (const float*)d_in[8];
    const float* bM  = (const float*)d_in[9];
    const float* uL  = (const float*)d_in[10];
    // d_in[11] = wL: softmax over [1,1] == 1.0
    const float* laL = (const float*)d_in[12];
    const float* bL  = (const float*)d_in[13];
    const float* W1  = (const float*)d_in[14];
    const float* b1  = (const float*)d_in[15];
    const float* W2  = (const float*)d_in[16];
    const float* b2  = (const float*)d_in[17];
    const float* W3  = (const float*)d_in[18];
    const float* b3  = (const float*)d_in[19];
    float* out = (float*)d_out;

    char* ws = (char*)d_ws;
    char*     Gz   = ws + GOFF;
    _Float16* W2hi = (_Float16*)(ws + W2HI);
    _Float16* W2lo = (_Float16*)(ws + W2LO);
    float*    CgF  = (float*)(ws + CGOFF);

    prep_kernel<<<25, 256, 0, stream>>>(u0, w0, la0, b0, uM, wM, laM, bM,
                                        uL, laL, W1, b1, W2, b2, W3,
                                        Gz, W2hi, W2lo, CgF);

    static bool attr_set = false;
    if (!attr_set) {
        hipFuncSetAttribute((const void*)mono_main,
                            hipFuncAttributeMaxDynamicSharedMemorySize, 131072);
        attr_set = true;
    }
    mono_main<<<256, 512, 131072, stream>>>(x, fy0, Gz, W2hi, W2lo, CgF, b3, bL, out);
}